// Round 20
// baseline (122.199 us; speedup 1.0000x reference)
//
#include <hip/hip_runtime.h>
#include <stdint.h>

#define B_ 2
#define S_ 2048
#define D_ 1024
#define H_ 16
#define C_ 64
#define M_ (B_*S_)     // 4096 tokens
#define N1_ (3*D_)     // 3072 qkv cols

typedef float f32x4 __attribute__((ext_vector_type(4)));
typedef float f32x16 __attribute__((ext_vector_type(16)));
typedef __bf16 bf16x8 __attribute__((ext_vector_type(8)));

#define QSCALE 0.18033688f   /* 1/sqrt(64) * log2(e), folded into Q */

// compiler-generated bf16 convert (fuses pairs into v_cvt_pk_bf16_f32)
static __device__ __forceinline__ unsigned short f2bf(float f) {
  __bf16 h = (__bf16)f;
  return __builtin_bit_cast(unsigned short, h);
}
static __device__ __forceinline__ unsigned pk2(float lo, float hi) {
  return (unsigned)f2bf(lo) | ((unsigned)f2bf(hi) << 16);
}

static __device__ __forceinline__ f32x4 mfma_bf16(uint4 a, uint4 b, f32x4 c) {
  return __builtin_amdgcn_mfma_f32_16x16x32_bf16(
      __builtin_bit_cast(bf16x8, a), __builtin_bit_cast(bf16x8, b), c, 0, 0, 0);
}
static __device__ __forceinline__ f32x16 mfma32(uint4 a, uint4 b, f32x16 c) {
  return __builtin_amdgcn_mfma_f32_32x32x16_bf16(
      __builtin_bit_cast(bf16x8, a), __builtin_bit_cast(bf16x8, b), c, 0, 0, 0);
}

static __device__ __forceinline__ unsigned xswap32(unsigned x) {
  return (unsigned)__shfl_xor((int)x, 32);
}

// async global->LDS, 16B per lane; lds dest is wave-uniform base + lane*16
static __device__ __forceinline__ void gload16(const void* g, void* l) {
  __builtin_amdgcn_global_load_lds(
      (const __attribute__((address_space(1))) unsigned int*)g,
      (__attribute__((address_space(3))) unsigned int*)l, 16, 0, 0);
}

// ---------------- fused cast fp32 -> bf16 for x, W_qkv, W_out ---------
#define N8X (M_*D_/8)
#define N8W (N1_*D_/8)
#define N8O (D_*D_/8)
__global__ __launch_bounds__(256) void cast_all(
    const float* __restrict__ x,   unsigned short* __restrict__ xb,
    const float* __restrict__ wq,  unsigned short* __restrict__ wqb,
    const float* __restrict__ wo,  unsigned short* __restrict__ wob) {
  int i = blockIdx.x * 256 + threadIdx.x;
  const float* src; unsigned short* dst; int j;
  if (i < N8X)              { src = x;  dst = xb;  j = i; }
  else if (i < N8X + N8W)   { src = wq; dst = wqb; j = i - N8X; }
  else                      { src = wo; dst = wob; j = i - N8X - N8W; }
  const float4* s4 = (const float4*)src;
  float4 a = s4[2*j], b = s4[2*j+1];
  uint4 o;
  o.x = pk2(a.x, a.y);
  o.y = pk2(a.z, a.w);
  o.z = pk2(b.x, b.y);
  o.w = pk2(b.z, b.w);
  ((uint4*)dst)[j] = o;
}

// ---------------- GEMM: C[m][n] = sum_k A[m][k]*B[n][k] + bias[n] ----
// BK=64, double-buffered (T3 2-phase; R16-verified). No XCD swizzle (R17
// showed -2% when L3-fit). Linear LDS dest, pre-swizzled source chunk.
// MODE 0: Cf fp32.
// MODE 1: Qg [b][h][s][64] (pre-scaled); K/V in FRAGMENT-LINEAR layout:
//   Kf slab idx = (((bh*32+kvb)*2+half)*4+kc)*512 + (hi*32+ql)*8 + j
//   Vf slab idx = (((bh*32+kvb)*2+dhalf)*4+kc)*512 + (hi*32+ql)*8 + j
template<int MODE>
__global__ __launch_bounds__(256) void gemm_bt(
    const unsigned short* __restrict__ A,
    const unsigned short* __restrict__ Bm,
    const float* __restrict__ bias,
    float* __restrict__ Cf,
    unsigned short* __restrict__ Qg,
    unsigned short* __restrict__ Kf,
    unsigned short* __restrict__ Vf,
    int Ndim, int Kdim)
{
  __shared__ __attribute__((aligned(16))) unsigned short As[2][128*64];
  __shared__ __attribute__((aligned(16))) unsigned short Bs[2][128*64];
  const int tid = threadIdx.x;
  const int l = tid & 63, wid = tid >> 6;
  const int g = l >> 4, lr = l & 15;
  const int m0 = blockIdx.y * 128, n0 = blockIdx.x * 128;
  const int wr = (wid >> 1) * 64, wc = (wid & 1) * 64;

  f32x4 acc[4][4] = {};

  // staging: wave wid owns rows [wid*32, wid*32+32); 4 insts of 8 rows each.
  // lane l -> row (l>>3) within group, position l&7; source chunk = (l&7)^(l>>3)
  const int srow8 = l >> 3;
  const int schunk = (l & 7) ^ srow8;
  const unsigned short* Agl = A + (size_t)(m0 + wid*32 + srow8) * Kdim + schunk*8;
  const unsigned short* Bgl = Bm + (size_t)(n0 + wid*32 + srow8) * Kdim + schunk*8;
  const int doff = (wid*32)*64;          // dest offset within a buffer
  const size_t rstep = (size_t)8 * Kdim;

#define GSTAGE(BI, K0) do {                                        \
    _Pragma("unroll")                                              \
    for (int i_ = 0; i_ < 4; ++i_) {                               \
      gload16(Agl + (K0) + i_*rstep, &As[BI][doff + i_*8*64]);     \
      gload16(Bgl + (K0) + i_*rstep, &Bs[BI][doff + i_*8*64]);     \
    }                                                              \
  } while (0)

  GSTAGE(0, 0);
  __syncthreads();                       // implicit vmcnt(0): tile 0 visible

  int cur = 0;
  for (int k0 = 0; k0 < Kdim; k0 += 64) {
    if (k0 + 64 < Kdim) GSTAGE(cur ^ 1, k0 + 64);   // in flight over compute
    const unsigned short* Ab = As[cur];
    const unsigned short* Bb = Bs[cur];
#pragma unroll
    for (int kk = 0; kk < 2; ++kk) {
      const int c = kk*4 + g;
      uint4 af[4], bf[4];
#pragma unroll
      for (int mi = 0; mi < 4; ++mi)
        af[mi] = *(const uint4*)&Ab[(wr + mi*16 + lr)*64 + ((c ^ (lr & 7))*8)];
#pragma unroll
      for (int ni = 0; ni < 4; ++ni)
        bf[ni] = *(const uint4*)&Bb[(wc + ni*16 + lr)*64 + ((c ^ (lr & 7))*8)];
#pragma unroll
      for (int mi = 0; mi < 4; ++mi)
#pragma unroll
        for (int ni = 0; ni < 4; ++ni)
          acc[mi][ni] = mfma_bf16(af[mi], bf[ni], acc[mi][ni]);
    }
    __syncthreads();                     // drains vmcnt (next tile) + readers
    cur ^= 1;
  }
#undef GSTAGE

#pragma unroll
  for (int mi = 0; mi < 4; ++mi)
#pragma unroll
    for (int ni = 0; ni < 4; ++ni) {
      if (MODE == 0) {
#pragma unroll
        for (int r = 0; r < 4; ++r) {
          const int row = m0 + wr + mi*16 + g*4 + r;
          const int col = n0 + wc + ni*16 + lr;
          Cf[(size_t)row * Ndim + col] = acc[mi][ni][r] + bias[col];
        }
      } else {
        const int colbase = n0 + wc + ni*16;         // multiple of 16
        const int h     = colbase / 192;             // uniform over the 16 lanes
        const int rem   = colbase % 192;
        const int which = rem >> 6;                  // 0=Q 1=K 2=V, uniform
        const int cb    = rem & 63;                  // multiple of 16
        const float bv  = bias[colbase + lr];
        const int row0  = m0 + wr + mi*16 + g*4;     // 4 consecutive rows
        const int b     = row0 >> 11, s0 = row0 & 2047;
        const size_t bh32 = (size_t)(b*H_ + h) * 32;
        if (which == 0) {
#pragma unroll
          for (int r = 0; r < 4; ++r) {
            const float v = (acc[mi][ni][r] + bv) * QSCALE;
            Qg[((size_t)(b*H_ + h)*S_ + (s0 + r))*C_ + cb + lr] = f2bf(v);
          }
        } else if (which == 1) {
          // K fragment-linear: c = cb+lr -> kc,hi,j ; s -> kvb,half,ql
          const int kc = cb >> 4, hi = lr >> 3, j = lr & 7;
          const int kvb = s0 >> 6, kq = s0 & 63;
          const int half = kq >> 5, qlb = kq & 31;
          const size_t base = (((bh32 + kvb)*2 + half)*4 + kc)*512 + hi*256 + j;
#pragma unroll
          for (int r = 0; r < 4; ++r)
            Kf[base + (size_t)(qlb + r)*8] = f2bf(acc[mi][ni][r] + bv);
        } else {
          // V fragment-linear: d = cb+lr -> dhalf,ql ; kv = s -> kvb,kc,hi,j0
          const int d = cb + lr;
          const int dhalf = d >> 5, ql = d & 31;
          const int kvb = s0 >> 6, kq = s0 & 63;
          const int kc = kq >> 4, hi = (kq >> 3) & 1, j0 = kq & 7;
          const size_t base = (((bh32 + kvb)*2 + dhalf)*4 + kc)*512
                              + (hi*32 + ql)*8 + j0;
          ushort4 pk;
          pk.x = f2bf(acc[mi][ni][0] + bv);
          pk.y = f2bf(acc[mi][ni][1] + bv);
          pk.z = f2bf(acc[mi][ni][2] + bv);
          pk.w = f2bf(acc[mi][ni][3] + bv);
          *(ushort4*)(Vf + base) = pk;
        }
      }
    }
}

// ---------------- causal flash attention, split-K over waves ----------
// grid (x=bh=32, y -> qt=63-y): bh%8 = XCD -> each head's K/V pinned to one L2.
// 4 waves interleave kv64 blocks (i = w, w+4, ...) of ONE 32-row q-tile.
// Fixed-max softmax (P = exp2(s)) => partials additive; 2-level LDS combine.
// P -> PV B-fragments via pk2 + 8 shfl_xor(32) (R19). NEW (R20): lsum on the
// MATRIX pipe — mfma32(ones, pb[kc], lacc) accumulates column sums of P,
// replacing the 23-add VALU tree + its serial chain (attn is VALU-bound).
#define PS_ 72   /* Pw row stride in elements; epilogue/combine only */
__global__ __launch_bounds__(256) void attn_fwd(
    const unsigned short* __restrict__ Qg,
    const unsigned short* __restrict__ Kf,
    const unsigned short* __restrict__ Vf,
    unsigned short* __restrict__ ctx)
{
  __shared__ __attribute__((aligned(16))) unsigned short Ps[4][32*PS_]; // 18432 B
  float* Cmb0 = (float*)&Ps[0][0];         // aliased combine region 0 (2112 f32)
  float* Cmb1 = Cmb0 + 2112;               // region 1

  const int tid = threadIdx.x, l = tid & 63, w = tid >> 6;
  const int ql = l & 31, hi = l >> 5;
  const int bh = blockIdx.x;
  const int qt = 63 - (int)blockIdx.y;     // heavy tiles dispatched first
  const int qw0 = qt * 32;
  const int qg = qw0 + ql;
  const size_t baseK = (size_t)bh * S_ * C_;

  // Q fragments: B-operand, 4 k-chunks of 16 (C=64)
  uint4 qreg[4];
  {
    const unsigned short* qp = Qg + baseK + (size_t)qg * C_ + hi * 8;
#pragma unroll
    for (int kc = 0; kc < 4; ++kc) qreg[kc] = *(const uint4*)(qp + 16*kc);
  }

  f32x16 acc0 = {}, acc1 = {}, lacc = {};
  const uint4 ones = (uint4){0x3F803F80u, 0x3F803F80u, 0x3F803F80u, 0x3F803F80u};

  // fragment-linear per-lane pointers: slab stride 512 elems, kvb stride 4096
  const unsigned short* pK = Kf + (size_t)bh * (32*4096) + (size_t)l * 8;
  const unsigned short* pV = Vf + (size_t)bh * (32*4096) + (size_t)l * 8;
  unsigned short* Pw = Ps[w];

  const int n_t = (qt + 2) >> 1;           // kv64 blocks for this q-tile
  for (int i = w; i < n_t; i += 4) {       // wave-interleaved split-K
    const int kv0 = i * 64;
    const size_t kb = (size_t)i * 4096;

    // ---- K fragments (contiguous 1KB bursts) + QK^T ----
    uint4 kf0[4], kf1[4];
#pragma unroll
    for (int kc = 0; kc < 4; ++kc) {
      kf0[kc] = *(const uint4*)(pK + kb + kc*512);          // half 0
      kf1[kc] = *(const uint4*)(pK + kb + 2048 + kc*512);   // half 1
    }
    f32x16 st0 = {}, st1 = {};
    __builtin_amdgcn_s_setprio(1);
#pragma unroll
    for (int kc = 0; kc < 4; ++kc) {
      st0 = mfma32(kf0[kc], qreg[kc], st0);
      st1 = mfma32(kf1[kc], qreg[kc], st1);
    }
    __builtin_amdgcn_s_setprio(0);

    // ---- V fragments issued early: latency hides under softmax ----
    uint4 vf0[4], vf1[4];
#pragma unroll
    for (int kc = 0; kc < 4; ++kc) {
      vf0[kc] = *(const uint4*)(pV + kb + kc*512);          // dhalf 0
      vf1[kc] = *(const uint4*)(pV + kb + 2048 + kc*512);   // dhalf 1
    }

    // ---- mask (diagonal block only) ----
    if (kv0 + 63 > qw0) {
#pragma unroll
      for (int r = 0; r < 16; ++r) {
        const int krow = (r & 3) + 8*(r >> 2) + 4*hi;
        if (kv0 + krow      > qg) st0[r] = -1e30f;
        if (kv0 + 32 + krow > qg) st1[r] = -1e30f;
      }
    }

    // ---- fixed-max softmax: P = exp2(s) directly (sum via MFMA below) ----
#pragma unroll
    for (int r = 0; r < 16; ++r) {
      st0[r] = exp2f(st0[r]);
      st1[r] = exp2f(st1[r]);
    }

    // ---- P -> bf16 B-fragments via pk2 + shfl_xor(32) exchange ----
    // W[m] pairs: W0,W1 = keys 4hi+0..3; W2,W3 = 8+4hi+0..3;
    //             W4,W5 = 16+4hi+0..3; W6,W7 = 24+4hi+0..3 (per st-block).
    // Partner needs: hi=0 sends W2,W3,W6,W7; hi=1 sends W0,W1,W4,W5.
    uint4 pb[4];
#pragma unroll
    for (int s = 0; s < 2; ++s) {
      unsigned W0, W1, W2, W3, W4, W5, W6, W7;
      if (s == 0) {
        W0 = pk2(st0[0], st0[1]);   W1 = pk2(st0[2], st0[3]);
        W2 = pk2(st0[4], st0[5]);   W3 = pk2(st0[6], st0[7]);
        W4 = pk2(st0[8], st0[9]);   W5 = pk2(st0[10], st0[11]);
        W6 = pk2(st0[12], st0[13]); W7 = pk2(st0[14], st0[15]);
      } else {
        W0 = pk2(st1[0], st1[1]);   W1 = pk2(st1[2], st1[3]);
        W2 = pk2(st1[4], st1[5]);   W3 = pk2(st1[6], st1[7]);
        W4 = pk2(st1[8], st1[9]);   W5 = pk2(st1[10], st1[11]);
        W6 = pk2(st1[12], st1[13]); W7 = pk2(st1[14], st1[15]);
      }
      const unsigned T0 = hi ? W0 : W2, T1 = hi ? W1 : W3;
      const unsigned T2 = hi ? W4 : W6, T3 = hi ? W5 : W7;
      const unsigned U0 = xswap32(T0), U1 = xswap32(T1);
      const unsigned U2 = xswap32(T2), U3 = xswap32(T3);
      uint4 pa, pbv;
      pa.x  = hi ? U0 : W0;  pa.y  = hi ? U1 : W1;
      pa.z  = hi ? W2 : U0;  pa.w  = hi ? W3 : U1;
      pbv.x = hi ? U2 : W4;  pbv.y = hi ? U3 : W5;
      pbv.z = hi ? W6 : U2;  pbv.w = hi ? W7 : U3;
      pb[2*s]   = pa;
      pb[2*s+1] = pbv;
    }

    // ---- PV (+ lsum via ones-MFMA): 12 MFMAs, no VALU reduction ----
    __builtin_amdgcn_s_setprio(1);
#pragma unroll
    for (int kc = 0; kc < 4; ++kc) {
      acc0 = mfma32(vf0[kc], pb[kc], acc0);
      acc1 = mfma32(vf1[kc], pb[kc], acc1);
      lacc = mfma32(ones,    pb[kc], lacc);
    }
    __builtin_amdgcn_s_setprio(0);
  }

  // every lane now holds the FULL partial sum for its q-row in lacc[0]
  float lsum = lacc[0];

  // ---- combine partials across waves (LDS tree aliased onto Ps) ----
  __syncthreads();                         // all waves reached the combine
  if (w >= 2) {
    float* Cb = (w == 2) ? Cmb0 : Cmb1;
#pragma unroll
    for (int r = 0; r < 16; ++r) {
      const int d0 = (r & 3) + 8*(r >> 2) + 4*hi;
      Cb[d0*32 + ql]        = acc0[r];
      Cb[(d0 + 32)*32 + ql] = acc1[r];
    }
    Cb[2048 + l] = lsum;
  }
  __syncthreads();
  if (w < 2) {
    const float* Cb = (w == 0) ? Cmb0 : Cmb1;
#pragma unroll
    for (int r = 0; r < 16; ++r) {
      const int d0 = (r & 3) + 8*(r >> 2) + 4*hi;
      acc0[r] += Cb[d0*32 + ql];
      acc1[r] += Cb[(d0 + 32)*32 + ql];
    }
    lsum += Cb[2048 + l];
  }
  __syncthreads();
  if (w == 1) {
    float* Cb = Cmb0;
#pragma unroll
    for (int r = 0; r < 16; ++r) {
      const int d0 = (r & 3) + 8*(r >> 2) + 4*hi;
      Cb[d0*32 + ql]        = acc0[r];
      Cb[(d0 + 32)*32 + ql] = acc1[r];
    }
    Cb[2048 + l] = lsum;
  }
  __syncthreads();
  if (w != 0) return;
  {
    const float* Cb = Cmb0;
#pragma unroll
    for (int r = 0; r < 16; ++r) {
      const int d0 = (r & 3) + 8*(r >> 2) + 4*hi;
      acc0[r] += Cb[d0*32 + ql];
      acc1[r] += Cb[(d0 + 32)*32 + ql];
    }
    lsum += Cb[2048 + l];
  }

  // ---- epilogue (wave 0): normalize, LDS transpose, coalesced store ----
  const float inv = 1.0f / lsum;           // full sum (no cross-half shuffle)
#pragma unroll
  for (int r = 0; r < 16; ++r) {
    const int d0 = (r & 3) + 8*(r >> 2) + 4*hi;
    Pw[ql*PS_ + ( d0       ^ (8*(ql & 7)))] = f2bf(acc0[r] * inv);
    Pw[ql*PS_ + ((32 + d0) ^ (8*(ql & 7)))] = f2bf(acc1[r] * inv);
  }
  const int q1 = l >> 1, half = l & 1;
  const unsigned short* Er = Pw + q1*PS_;
  const int b = bh >> 4, h = bh & 15;
  unsigned short* outp = ctx + ((size_t)(b*S_ + qw0 + q1))*D_ + h*C_;
#pragma unroll
  for (int j = 0; j < 4; ++j) {
    const int clog = half*4 + j;
    const int cx = clog ^ (q1 & 7);
    uint4 val = *(const uint4*)&Er[cx*8];
    *(uint4*)(outp + clog*8) = val;
  }
}

// ---------------- launch ---------------------------------------------
extern "C" void kernel_launch(void* const* d_in, const int* in_sizes, int n_in,
                              void* d_out, int out_size, void* d_ws, size_t ws_size,
                              hipStream_t stream) {
  const float* x    = (const float*)d_in[0];
  const float* Wqkv = (const float*)d_in[1];
  const float* bqkv = (const float*)d_in[2];
  const float* Wout = (const float*)d_in[3];
  const float* bout = (const float*)d_in[4];
  float* out = (float*)d_out;

  unsigned short* ws = (unsigned short*)d_ws;
  unsigned short* xb    = ws;
  unsigned short* wqkvb = xb    + (size_t)M_ * D_;
  unsigned short* woutb = wqkvb + (size_t)N1_ * D_;
  unsigned short* Qb    = woutb + (size_t)D_ * D_;
  unsigned short* Kfb   = Qb    + (size_t)B_*H_*S_*C_;
  unsigned short* Vfb   = Kfb   + (size_t)B_*H_*S_*C_;
  unsigned short* ctxb  = Vfb   + (size_t)B_*H_*S_*C_;

  {
    const int ntot = N8X + N8W + N8O;
    cast_all<<<dim3((ntot+255)/256), dim3(256), 0, stream>>>(
        x, xb, Wqkv, wqkvb, Wout, woutb);
  }

  gemm_bt<1><<<dim3(N1_/128, M_/128), dim3(256), 0, stream>>>(
      xb, wqkvb, bqkv, nullptr, Qb, Kfb, Vfb, N1_, D_);

  attn_fwd<<<dim3(32, 64), dim3(256), 0, stream>>>(Qb, Kfb, Vfb, ctxb);

  gemm_bt<0><<<dim3(D_/128, M_/128), dim3(256), 0, stream>>>(
      ctxb, woutb, bout, out, nullptr, nullptr, nullptr, D_, D_);
}

// Round 21
// 118.300 us; speedup vs baseline: 1.0330x; 1.0330x over previous
//
#include <hip/hip_runtime.h>
#include <stdint.h>

#define B_ 2
#define S_ 2048
#define D_ 1024
#define H_ 16
#define C_ 64
#define M_ (B_*S_)     // 4096 tokens
#define N1_ (3*D_)     // 3072 qkv cols

typedef float f32x4 __attribute__((ext_vector_type(4)));
typedef float f32x16 __attribute__((ext_vector_type(16)));
typedef __bf16 bf16x8 __attribute__((ext_vector_type(8)));

#define QSCALE 0.18033688f   /* 1/sqrt(64) * log2(e), folded into Q */

// compiler-generated bf16 convert (fuses pairs into v_cvt_pk_bf16_f32)
static __device__ __forceinline__ unsigned short f2bf(float f) {
  __bf16 h = (__bf16)f;
  return __builtin_bit_cast(unsigned short, h);
}
static __device__ __forceinline__ unsigned pk2(float lo, float hi) {
  return (unsigned)f2bf(lo) | ((unsigned)f2bf(hi) << 16);
}

static __device__ __forceinline__ f32x4 mfma_bf16(uint4 a, uint4 b, f32x4 c) {
  return __builtin_amdgcn_mfma_f32_16x16x32_bf16(
      __builtin_bit_cast(bf16x8, a), __builtin_bit_cast(bf16x8, b), c, 0, 0, 0);
}
static __device__ __forceinline__ f32x16 mfma32(uint4 a, uint4 b, f32x16 c) {
  return __builtin_amdgcn_mfma_f32_32x32x16_bf16(
      __builtin_bit_cast(bf16x8, a), __builtin_bit_cast(bf16x8, b), c, 0, 0, 0);
}

// cross-half combine via shfl (known-correct HIP semantics on wave64)
static __device__ __forceinline__ float xsum32(float x) {
  return x + __shfl_xor(x, 32);
}

// async global->LDS, 16B per lane; lds dest is wave-uniform base + lane*16
static __device__ __forceinline__ void gload16(const void* g, void* l) {
  __builtin_amdgcn_global_load_lds(
      (const __attribute__((address_space(1))) unsigned int*)g,
      (__attribute__((address_space(3))) unsigned int*)l, 16, 0, 0);
}

// ---------------- fused cast fp32 -> bf16 for x, W_qkv, W_out ---------
#define N8X (M_*D_/8)
#define N8W (N1_*D_/8)
#define N8O (D_*D_/8)
__global__ __launch_bounds__(256) void cast_all(
    const float* __restrict__ x,   unsigned short* __restrict__ xb,
    const float* __restrict__ wq,  unsigned short* __restrict__ wqb,
    const float* __restrict__ wo,  unsigned short* __restrict__ wob) {
  int i = blockIdx.x * 256 + threadIdx.x;
  const float* src; unsigned short* dst; int j;
  if (i < N8X)              { src = x;  dst = xb;  j = i; }
  else if (i < N8X + N8W)   { src = wq; dst = wqb; j = i - N8X; }
  else                      { src = wo; dst = wob; j = i - N8X - N8W; }
  const float4* s4 = (const float4*)src;
  float4 a = s4[2*j], b = s4[2*j+1];
  uint4 o;
  o.x = pk2(a.x, a.y);
  o.y = pk2(a.z, a.w);
  o.z = pk2(b.x, b.y);
  o.w = pk2(b.z, b.w);
  ((uint4*)dst)[j] = o;
}

// ---------------- GEMM: C[m][n] = sum_k A[m][k]*B[n][k] + bias[n] ----
// BK=64, DOUBLE-BUFFERED (T3 minimum 2-phase): next tile's gload16s issue
// BEFORE computing the current tile; ONE barrier per K-step (its implicit
// vmcnt(0) is cheap since loads had the whole compute phase in flight).
// Linear LDS dest, pre-swizzled source chunk (l&7)^(l>>3), read swizzle c^(r&7).
// MODE 0: Cf fp32.
// MODE 1: Qg [b][h][s][64] (pre-scaled); K/V in FRAGMENT-LINEAR layout:
//   Kf slab idx = (((bh*32+kvb)*2+half)*4+kc)*512 + (hi*32+ql)*8 + j
//   Vf slab idx = (((bh*32+kvb)*2+dhalf)*4+kc)*512 + (hi*32+ql)*8 + j
template<int MODE>
__global__ __launch_bounds__(256) void gemm_bt(
    const unsigned short* __restrict__ A,
    const unsigned short* __restrict__ Bm,
    const float* __restrict__ bias,
    float* __restrict__ Cf,
    unsigned short* __restrict__ Qg,
    unsigned short* __restrict__ Kf,
    unsigned short* __restrict__ Vf,
    int Ndim, int Kdim)
{
  __shared__ __attribute__((aligned(16))) unsigned short As[2][128*64];
  __shared__ __attribute__((aligned(16))) unsigned short Bs[2][128*64];
  const int tid = threadIdx.x;
  const int l = tid & 63, wid = tid >> 6;
  const int g = l >> 4, lr = l & 15;
  const int m0 = blockIdx.y * 128, n0 = blockIdx.x * 128;
  const int wr = (wid >> 1) * 64, wc = (wid & 1) * 64;

  f32x4 acc[4][4] = {};

  // staging: wave wid owns rows [wid*32, wid*32+32); 4 insts of 8 rows each.
  // lane l -> row (l>>3) within group, position l&7; source chunk = (l&7)^(l>>3)
  const int srow8 = l >> 3;
  const int schunk = (l & 7) ^ srow8;
  const unsigned short* Agl = A + (size_t)(m0 + wid*32 + srow8) * Kdim + schunk*8;
  const unsigned short* Bgl = Bm + (size_t)(n0 + wid*32 + srow8) * Kdim + schunk*8;
  const int doff = (wid*32)*64;          // dest offset within a buffer
  const size_t rstep = (size_t)8 * Kdim;

#define GSTAGE(BI, K0) do {                                        \
    _Pragma("unroll")                                              \
    for (int i_ = 0; i_ < 4; ++i_) {                               \
      gload16(Agl + (K0) + i_*rstep, &As[BI][doff + i_*8*64]);     \
      gload16(Bgl + (K0) + i_*rstep, &Bs[BI][doff + i_*8*64]);     \
    }                                                              \
  } while (0)

  GSTAGE(0, 0);
  __syncthreads();                       // implicit vmcnt(0): tile 0 visible

  int cur = 0;
  for (int k0 = 0; k0 < Kdim; k0 += 64) {
    if (k0 + 64 < Kdim) GSTAGE(cur ^ 1, k0 + 64);   // in flight over compute
    const unsigned short* Ab = As[cur];
    const unsigned short* Bb = Bs[cur];
#pragma unroll
    for (int kk = 0; kk < 2; ++kk) {
      const int c = kk*4 + g;
      uint4 af[4], bf[4];
#pragma unroll
      for (int mi = 0; mi < 4; ++mi)
        af[mi] = *(const uint4*)&Ab[(wr + mi*16 + lr)*64 + ((c ^ (lr & 7))*8)];
#pragma unroll
      for (int ni = 0; ni < 4; ++ni)
        bf[ni] = *(const uint4*)&Bb[(wc + ni*16 + lr)*64 + ((c ^ (lr & 7))*8)];
#pragma unroll
      for (int mi = 0; mi < 4; ++mi)
#pragma unroll
        for (int ni = 0; ni < 4; ++ni)
          acc[mi][ni] = mfma_bf16(af[mi], bf[ni], acc[mi][ni]);
    }
    __syncthreads();                     // drains vmcnt (next tile) + readers
    cur ^= 1;
  }
#undef GSTAGE

#pragma unroll
  for (int mi = 0; mi < 4; ++mi)
#pragma unroll
    for (int ni = 0; ni < 4; ++ni) {
      if (MODE == 0) {
#pragma unroll
        for (int r = 0; r < 4; ++r) {
          const int row = m0 + wr + mi*16 + g*4 + r;
          const int col = n0 + wc + ni*16 + lr;
          Cf[(size_t)row * Ndim + col] = acc[mi][ni][r] + bias[col];
        }
      } else {
        const int colbase = n0 + wc + ni*16;         // multiple of 16
        const int h     = colbase / 192;             // uniform over the 16 lanes
        const int rem   = colbase % 192;
        const int which = rem >> 6;                  // 0=Q 1=K 2=V, uniform
        const int cb    = rem & 63;                  // multiple of 16
        const float bv  = bias[colbase + lr];
        const int row0  = m0 + wr + mi*16 + g*4;     // 4 consecutive rows
        const int b     = row0 >> 11, s0 = row0 & 2047;
        const size_t bh32 = (size_t)(b*H_ + h) * 32;
        if (which == 0) {
#pragma unroll
          for (int r = 0; r < 4; ++r) {
            const float v = (acc[mi][ni][r] + bv) * QSCALE;
            Qg[((size_t)(b*H_ + h)*S_ + (s0 + r))*C_ + cb + lr] = f2bf(v);
          }
        } else if (which == 1) {
          // K fragment-linear: c = cb+lr -> kc,hi,j ; s -> kvb,half,ql
          const int kc = cb >> 4, hi = lr >> 3, j = lr & 7;
          const int kvb = s0 >> 6, kq = s0 & 63;
          const int half = kq >> 5, qlb = kq & 31;
          const size_t base = (((bh32 + kvb)*2 + half)*4 + kc)*512 + hi*256 + j;
#pragma unroll
          for (int r = 0; r < 4; ++r)
            Kf[base + (size_t)(qlb + r)*8] = f2bf(acc[mi][ni][r] + bv);
        } else {
          // V fragment-linear: d = cb+lr -> dhalf,ql ; kv = s -> kvb,kc,hi,j0
          const int d = cb + lr;
          const int dhalf = d >> 5, ql = d & 31;
          const int kvb = s0 >> 6, kq = s0 & 63;
          const int kc = kq >> 4, hi = (kq >> 3) & 1, j0 = kq & 7;
          const size_t base = (((bh32 + kvb)*2 + dhalf)*4 + kc)*512
                              + (hi*32 + ql)*8 + j0;
          ushort4 pk;
          pk.x = f2bf(acc[mi][ni][0] + bv);
          pk.y = f2bf(acc[mi][ni][1] + bv);
          pk.z = f2bf(acc[mi][ni][2] + bv);
          pk.w = f2bf(acc[mi][ni][3] + bv);
          *(ushort4*)(Vf + base) = pk;
        }
      }
    }
}

// ---------------- causal flash attention, split-K over waves ----------
// grid (x=bh=32, y -> qt=63-y): bh%8 = XCD -> each head's K/V pinned to one L2.
// 4 waves interleave kv64 blocks (i = w, w+4, ...) of ONE 32-row q-tile.
// Fixed-max softmax (P = exp2(s)) makes partials additive; combine via
// LDS tree ALIASED onto Ps (barrier before reuse). Longest chain 32 -> 8 iters.
// K/V fragment-linear (R12): every load is a contiguous 1KB burst.
#define PS_ 72   /* Pw row stride in elements; 144B = multiple of 16 */
__global__ __launch_bounds__(256) void attn_fwd(
    const unsigned short* __restrict__ Qg,
    const unsigned short* __restrict__ Kf,
    const unsigned short* __restrict__ Vf,
    unsigned short* __restrict__ ctx)
{
  __shared__ __attribute__((aligned(16))) unsigned short Ps[4][32*PS_]; // 18432 B
  float* Cmb0 = (float*)&Ps[0][0];         // aliased combine region 0 (2112 f32)
  float* Cmb1 = Cmb0 + 2112;               // region 1

  const int tid = threadIdx.x, l = tid & 63, w = tid >> 6;
  const int ql = l & 31, hi = l >> 5;
  const int bh = blockIdx.x;
  const int qt = 63 - (int)blockIdx.y;     // heavy tiles dispatched first
  const int qw0 = qt * 32;
  const int qg = qw0 + ql;
  const size_t baseK = (size_t)bh * S_ * C_;

  // Q fragments: B-operand, 4 k-chunks of 16 (C=64)
  uint4 qreg[4];
  {
    const unsigned short* qp = Qg + baseK + (size_t)qg * C_ + hi * 8;
#pragma unroll
    for (int kc = 0; kc < 4; ++kc) qreg[kc] = *(const uint4*)(qp + 16*kc);
  }

  f32x16 acc0 = {}, acc1 = {};
  float lsum = 0.f;

  // fragment-linear per-lane pointers: slab stride 512 elems, kvb stride 4096
  const unsigned short* pK = Kf + (size_t)bh * (32*4096) + (size_t)l * 8;
  const unsigned short* pV = Vf + (size_t)bh * (32*4096) + (size_t)l * 8;
  unsigned short* Pw = Ps[w];

  const int n_t = (qt + 2) >> 1;           // kv64 blocks for this q-tile
  for (int i = w; i < n_t; i += 4) {       // wave-interleaved split-K
    const int kv0 = i * 64;
    const size_t kb = (size_t)i * 4096;

    // ---- K fragments (contiguous 1KB bursts) + QK^T ----
    uint4 kf0[4], kf1[4];
#pragma unroll
    for (int kc = 0; kc < 4; ++kc) {
      kf0[kc] = *(const uint4*)(pK + kb + kc*512);          // half 0
      kf1[kc] = *(const uint4*)(pK + kb + 2048 + kc*512);   // half 1
    }
    f32x16 st0 = {}, st1 = {};
    __builtin_amdgcn_s_setprio(1);
#pragma unroll
    for (int kc = 0; kc < 4; ++kc) {
      st0 = mfma32(kf0[kc], qreg[kc], st0);
      st1 = mfma32(kf1[kc], qreg[kc], st1);
    }
    __builtin_amdgcn_s_setprio(0);

    // ---- V fragments issued early: latency hides under softmax ----
    uint4 vf0[4], vf1[4];
#pragma unroll
    for (int kc = 0; kc < 4; ++kc) {
      vf0[kc] = *(const uint4*)(pV + kb + kc*512);          // dhalf 0
      vf1[kc] = *(const uint4*)(pV + kb + 2048 + kc*512);   // dhalf 1
    }

    // ---- mask (diagonal block only) ----
    if (kv0 + 63 > qw0) {
#pragma unroll
      for (int r = 0; r < 16; ++r) {
        const int krow = (r & 3) + 8*(r >> 2) + 4*hi;
        if (kv0 + krow      > qg) st0[r] = -1e30f;
        if (kv0 + 32 + krow > qg) st1[r] = -1e30f;
      }
    }

    // ---- fixed-max softmax: P = exp2(s) directly ----
    float ps[8];
#pragma unroll
    for (int j = 0; j < 8; ++j) {
      st0[2*j]   = exp2f(st0[2*j]);
      st0[2*j+1] = exp2f(st0[2*j+1]);
      st1[2*j]   = exp2f(st1[2*j]);
      st1[2*j+1] = exp2f(st1[2*j+1]);
      ps[j] = (st0[2*j] + st0[2*j+1]) + (st1[2*j] + st1[2*j+1]);
    }
    ps[0] += ps[4]; ps[1] += ps[5]; ps[2] += ps[6]; ps[3] += ps[7];
    lsum += (ps[0] + ps[1]) + (ps[2] + ps[3]);

    // ---- P -> per-wave LDS Pw[q][key] (b64 writes), then B-fragments ----
#pragma unroll
    for (int r = 0; r < 16; r += 4) {
      const int k0i = (r >> 2)*8 + 4*hi;
      uint2 a0, a1;
      a0.x = pk2(st0[r],   st0[r+1]);  a0.y = pk2(st0[r+2], st0[r+3]);
      a1.x = pk2(st1[r],   st1[r+1]);  a1.y = pk2(st1[r+2], st1[r+3]);
      *(uint2*)&Pw[ql*PS_ + k0i]      = a0;
      *(uint2*)&Pw[ql*PS_ + 32 + k0i] = a1;
    }
    uint4 pb[4];
#pragma unroll
    for (int kc = 0; kc < 4; ++kc)
      pb[kc] = *(const uint4*)&Pw[ql*PS_ + kc*16 + hi*8];

    // ---- PV: accT[d][q] += V_frag x P_frag ----
    __builtin_amdgcn_s_setprio(1);
#pragma unroll
    for (int kc = 0; kc < 4; ++kc) {
      acc0 = mfma32(vf0[kc], pb[kc], acc0);
      acc1 = mfma32(vf1[kc], pb[kc], acc1);
    }
    __builtin_amdgcn_s_setprio(0);
  }

  // ---- combine partials across waves (LDS tree aliased onto Ps) ----
  __syncthreads();                         // everyone done with per-wave Pw
  if (w >= 2) {
    float* Cb = (w == 2) ? Cmb0 : Cmb1;
#pragma unroll
    for (int r = 0; r < 16; ++r) {
      const int d0 = (r & 3) + 8*(r >> 2) + 4*hi;
      Cb[d0*32 + ql]        = acc0[r];
      Cb[(d0 + 32)*32 + ql] = acc1[r];
    }
    Cb[2048 + l] = lsum;
  }
  __syncthreads();
  if (w < 2) {
    const float* Cb = (w == 0) ? Cmb0 : Cmb1;
#pragma unroll
    for (int r = 0; r < 16; ++r) {
      const int d0 = (r & 3) + 8*(r >> 2) + 4*hi;
      acc0[r] += Cb[d0*32 + ql];
      acc1[r] += Cb[(d0 + 32)*32 + ql];
    }
    lsum += Cb[2048 + l];
  }
  __syncthreads();
  if (w == 1) {
    float* Cb = Cmb0;
#pragma unroll
    for (int r = 0; r < 16; ++r) {
      const int d0 = (r & 3) + 8*(r >> 2) + 4*hi;
      Cb[d0*32 + ql]        = acc0[r];
      Cb[(d0 + 32)*32 + ql] = acc1[r];
    }
    Cb[2048 + l] = lsum;
  }
  __syncthreads();
  if (w != 0) return;
  {
    const float* Cb = Cmb0;
#pragma unroll
    for (int r = 0; r < 16; ++r) {
      const int d0 = (r & 3) + 8*(r >> 2) + 4*hi;
      acc0[r] += Cb[d0*32 + ql];
      acc1[r] += Cb[(d0 + 32)*32 + ql];
    }
    lsum += Cb[2048 + l];
  }

  // ---- epilogue (wave 0): normalize, LDS transpose, coalesced store ----
  const float inv = 1.0f / xsum32(lsum);
#pragma unroll
  for (int r = 0; r < 16; ++r) {
    const int d0 = (r & 3) + 8*(r >> 2) + 4*hi;
    Pw[ql*PS_ + ( d0       ^ (8*(ql & 7)))] = f2bf(acc0[r] * inv);
    Pw[ql*PS_ + ((32 + d0) ^ (8*(ql & 7)))] = f2bf(acc1[r] * inv);
  }
  const int q1 = l >> 1, half = l & 1;
  const unsigned short* Er = Pw + q1*PS_;
  const int b = bh >> 4, h = bh & 15;
  unsigned short* outp = ctx + ((size_t)(b*S_ + qw0 + q1))*D_ + h*C_;
#pragma unroll
  for (int j = 0; j < 4; ++j) {
    const int clog = half*4 + j;
    const int cx = clog ^ (q1 & 7);
    uint4 val = *(const uint4*)&Er[cx*8];
    *(uint4*)(outp + clog*8) = val;
  }
}

// ---------------- launch ---------------------------------------------
extern "C" void kernel_launch(void* const* d_in, const int* in_sizes, int n_in,
                              void* d_out, int out_size, void* d_ws, size_t ws_size,
                              hipStream_t stream) {
  const float* x    = (const float*)d_in[0];
  const float* Wqkv = (const float*)d_in[1];
  const float* bqkv = (const float*)d_in[2];
  const float* Wout = (const float*)d_in[3];
  const float* bout = (const float*)d_in[4];
  float* out = (float*)d_out;

  unsigned short* ws = (unsigned short*)d_ws;
  unsigned short* xb    = ws;
  unsigned short* wqkvb = xb    + (size_t)M_ * D_;
  unsigned short* woutb = wqkvb + (size_t)N1_ * D_;
  unsigned short* Qb    = woutb + (size_t)D_ * D_;
  unsigned short* Kfb   = Qb    + (size_t)B_*H_*S_*C_;
  unsigned short* Vfb   = Kfb   + (size_t)B_*H_*S_*C_;
  unsigned short* ctxb  = Vfb   + (size_t)B_*H_*S_*C_;

  {
    const int ntot = N8X + N8W + N8O;
    cast_all<<<dim3((ntot+255)/256), dim3(256), 0, stream>>>(
        x, xb, Wqkv, wqkvb, Wout, woutb);
  }

  gemm_bt<1><<<dim3(N1_/128, M_/128), dim3(256), 0, stream>>>(
      xb, wqkvb, bqkv, nullptr, Qb, Kfb, Vfb, N1_, D_);

  attn_fwd<<<dim3(32, 64), dim3(256), 0, stream>>>(Qb, Kfb, Vfb, ctxb);

  gemm_bt<0><<<dim3(D_/128, M_/128), dim3(256), 0, stream>>>(
      ctxb, woutb, bout, out, nullptr, nullptr, nullptr, D_, D_);
}